// Round 1
// baseline (507.610 us; speedup 1.0000x reference)
//
#include <hip/hip_runtime.h>
#include <math.h>

#define NEGC -1000000000.0f

__device__ __forceinline__ float softplusf(float v){ return log1pf(expf(v)); }

// ---------------- Kernel 1: W1 (256x128) -> w1t (128x256) ----------------
__global__ __launch_bounds__(256) void k_transpose(const float* __restrict__ W1,
                                                   float* __restrict__ w1t){
  int i = blockIdx.x * 256 + threadIdx.x;   // 0..32767
  if (i < 256 * 128){
    int k = i >> 7, d = i & 127;
    w1t[d * 256 + k] = W1[i];
  }
}

// ---------------- Kernel 2: scores[t] = tanh(x[t]·W1[k,:]) · W2 ----------------
// thread tid == k (0..255). 16 rows per group, register-blocked.
__global__ __launch_bounds__(256) void k_scores(const float* __restrict__ x,
                                                const float* __restrict__ w1t,
                                                const float* __restrict__ W2,
                                                float* __restrict__ scores, int T){
  __shared__ float scpart[4][16];
  const int tid  = threadIdx.x;
  const int k    = tid;
  const int lane = tid & 63;
  const int w    = tid >> 6;
  const float w2k = W2[k];

  for (int t0 = blockIdx.x * 16; t0 < T; t0 += gridDim.x * 16){
    int rb[16];
#pragma unroll
    for (int r = 0; r < 16; ++r){
      int rr = t0 + r; rr = (rr < T) ? rr : (T - 1);
      rb[r] = rr * 128;
    }
    float acc[16];
#pragma unroll
    for (int r = 0; r < 16; ++r) acc[r] = 0.f;

    for (int d = 0; d < 128; d += 4){
      // coalesced: 64 consecutive lanes read 64 consecutive floats
      const float w0 = w1t[(d + 0) * 256 + k];
      const float w1v= w1t[(d + 1) * 256 + k];
      const float w2v= w1t[(d + 2) * 256 + k];
      const float w3 = w1t[(d + 3) * 256 + k];
#pragma unroll
      for (int r = 0; r < 16; ++r){
        const float4 xv = *(const float4*)(x + rb[r] + d);  // uniform -> broadcast
        acc[r] = fmaf(xv.x, w0, acc[r]);
        acc[r] = fmaf(xv.y, w1v, acc[r]);
        acc[r] = fmaf(xv.z, w2v, acc[r]);
        acc[r] = fmaf(xv.w, w3, acc[r]);
      }
    }
#pragma unroll
    for (int r = 0; r < 16; ++r){
      float v = tanhf(acc[r]) * w2k;
      v += __shfl_xor(v, 1, 64);  v += __shfl_xor(v, 2, 64);
      v += __shfl_xor(v, 4, 64);  v += __shfl_xor(v, 8, 64);
      v += __shfl_xor(v, 16, 64); v += __shfl_xor(v, 32, 64);
      if (lane == 0) scpart[w][r] = v;
    }
    __syncthreads();
    if (tid < 16){
      int t = t0 + tid;
      if (t < T)
        scores[t] = scpart[0][tid] + scpart[1][tid] + scpart[2][tid] + scpart[3][tid];
    }
    __syncthreads();
  }
}

// ---------------- Kernel 3: per-segment UOT-badmm + pooled output ----------------
// 1024 threads: thread (n = tid>>3, j = tid&7) owns row n, cols j*16..j*16+15.
__global__ __launch_bounds__(1024) void k_uot(const float* __restrict__ x,
                                              const int*   __restrict__ batch,
                                              const float* __restrict__ scores,
                                              const float* __restrict__ a1r,
                                              const float* __restrict__ a2r,
                                              const float* __restrict__ a3r,
                                              float* __restrict__ out, int T){
  __shared__ float wavebuf[16][128];
  __shared__ float colbuf[128];
  __shared__ float lq0s[128];
  __shared__ int   sseg[2];
  __shared__ float sred[2];

  const int b    = blockIdx.x;
  const int tid  = threadIdx.x;
  const int n    = tid >> 3;
  const int j    = tid & 7;
  const int wvi  = tid >> 6;
  const int lane = tid & 63;

  if (tid == 0){
    int lo = 0, hi = T;
    while (lo < hi){ int mid = (lo + hi) >> 1; if (batch[mid] <  b) lo = mid + 1; else hi = mid; }
    int s0 = lo;
    hi = T;
    while (lo < hi){ int mid = (lo + hi) >> 1; if (batch[mid] <= b) lo = mid + 1; else hi = mid; }
    sseg[0] = s0; sseg[1] = lo - s0;
  }
  __syncthreads();
  const int start = sseg[0];
  const int nb    = sseg[1];

  // ---- segment softmax over scores -> log q0 ----
  if (tid < 128) lq0s[tid] = (tid < nb) ? scores[start + tid] : NEGC;
  __syncthreads();
  if (wvi == 0){
    float v0 = lq0s[lane], v1 = lq0s[lane + 64];
    float m = fmaxf(v0, v1);
#pragma unroll
    for (int msk = 32; msk; msk >>= 1) m = fmaxf(m, __shfl_xor(m, msk, 64));
    float s = expf(v0 - m) + expf(v1 - m);   // masked lanes underflow to 0
#pragma unroll
    for (int msk = 32; msk; msk >>= 1) s += __shfl_xor(s, msk, 64);
    if (lane == 0){ sred[0] = m; sred[1] = s; }
  }
  __syncthreads();
  const float smax   = sred[0];
  const float sdenom = sred[1] + 1e-16f;
  if (tid < 128){
    float l = NEGC;
    if (tid < nb){
      float q = expf(lq0s[tid] - smax) / sdenom;
      l = logf(q + 1e-8f);
    }
    lq0s[tid] = l;
  }
  __syncthreads();

  const float a1 = softplusf(a1r[0]);
  const float a2 = softplusf(a2r[0]);
  const float a3 = softplusf(a3r[0]);
  const float inv_a1 = 1.f / a1;
  const float log_p0 = logf(1.0f / 128.0f + 1e-8f);

  // mu-recursion: data-independent scalars (logsumexp(log_s,axis=1) == log_mu_old)
  float lmu_use[3];
  lmu_use[0] = log_p0;
  {
    float z1 = 0.f, lp = log_p0;
#pragma unroll
    for (int i = 1; i < 3; ++i){
      float nm = (a1 * lp + a2 * log_p0 - z1) / (a1 + a2);
      z1 += a1 * (expf(nm) - expf(lp));
      lmu_use[i] = nm; lp = nm;
    }
  }
  // eta-recursion: per-row scalars (logsumexp(log_t,axis=2) == log_eta_old)
  const float lq0 = lq0s[n];
  float leta_use[4];
  leta_use[0] = lq0;
  {
    float z2 = 0.f, lp = lq0;
#pragma unroll
    for (int i = 1; i < 4; ++i){
      float nm = (a1 * lp + a3 * lq0 - z2) / (a1 + a3);
      z2 += a1 * (expf(nm) - expf(lp));
      leta_use[i] = nm; lp = nm;
    }
  }

  const bool valid = (n < nb);
  float xd[16], z[16], ls[16];
  {
    const float* xp = x + (size_t)(start + n) * 128 + j * 16;
#pragma unroll
    for (int k = 0; k < 16; k += 4){
      float4 v = valid ? *(const float4*)(xp + k) : make_float4(0.f, 0.f, 0.f, 0.f);
      xd[k] = v.x; xd[k+1] = v.y; xd[k+2] = v.z; xd[k+3] = v.w;
    }
    const float lsi = lq0 + log_p0;
#pragma unroll
    for (int k = 0; k < 16; ++k){ z[k] = 0.f; ls[k] = lsi; }
  }

#pragma unroll
  for (int it = 0; it < 4; ++it){
    const float leta_i = leta_use[it];
    float y[16];
    float rmax = -3.402823e38f;
#pragma unroll
    for (int k = 0; k < 16; ++k){
      y[k] = (xd[k] - z[k]) * inv_a1 + ls[k];
      rmax = fmaxf(rmax, y[k]);
    }
    rmax = fmaxf(rmax, __shfl_xor(rmax, 1, 64));
    rmax = fmaxf(rmax, __shfl_xor(rmax, 2, 64));
    rmax = fmaxf(rmax, __shfl_xor(rmax, 4, 64));
    float rsum = 0.f;
#pragma unroll
    for (int k = 0; k < 16; ++k) rsum += expf(y[k] - rmax);
    rsum += __shfl_xor(rsum, 1, 64);
    rsum += __shfl_xor(rsum, 2, 64);
    rsum += __shfl_xor(rsum, 4, 64);
    const float rlse = rmax + logf(rsum);
    const float lof  = leta_i - rlse;
#pragma unroll
    for (int k = 0; k < 16; ++k) y[k] += lof;     // y = log_t

    if (it == 3){
      // output: out[b,d] = 128 * sum_n xd * exp(log_t)
#pragma unroll
      for (int k = 0; k < 16; ++k){
        float v = xd[k] * expf(y[k]);
        v += __shfl_xor(v, 8, 64);
        v += __shfl_xor(v, 16, 64);
        v += __shfl_xor(v, 32, 64);
        if (lane < 8) wavebuf[wvi][lane * 16 + k] = v;
      }
      __syncthreads();
      if (tid < 128){
        float s = 0.f;
#pragma unroll
        for (int wq = 0; wq < 16; ++wq) s += wavebuf[wq][tid];
        out[(size_t)b * 128 + tid] = 128.f * s;
      }
    } else {
      const float lmu_i = lmu_use[it];
      // column max of y2 = z/a1 + log_t
#pragma unroll
      for (int k = 0; k < 16; ++k){
        float v = z[k] * inv_a1 + y[k];
        v = fmaxf(v, __shfl_xor(v, 8, 64));
        v = fmaxf(v, __shfl_xor(v, 16, 64));
        v = fmaxf(v, __shfl_xor(v, 32, 64));
        if (lane < 8) wavebuf[wvi][lane * 16 + k] = v;
      }
      __syncthreads();                             // B1
      if (tid < 128){
        float m = -3.402823e38f;
#pragma unroll
        for (int wq = 0; wq < 16; ++wq) m = fmaxf(m, wavebuf[wq][tid]);
        colbuf[tid] = m;
      }
      __syncthreads();                             // B2
      // column sum of exp(y2 - cmax)
#pragma unroll
      for (int k = 0; k < 16; ++k){
        const float y2k = z[k] * inv_a1 + y[k];
        float v = expf(y2k - colbuf[j * 16 + k]);
        v += __shfl_xor(v, 8, 64);
        v += __shfl_xor(v, 16, 64);
        v += __shfl_xor(v, 32, 64);
        if (lane < 8) wavebuf[wvi][lane * 16 + k] = v;
      }
      __syncthreads();                             // B3
      if (tid < 128){
        float s = 0.f;
#pragma unroll
        for (int wq = 0; wq < 16; ++wq) s += wavebuf[wq][tid];
        colbuf[tid] = colbuf[tid] + logf(s);       // clse = cmax + log(csum)
      }
      __syncthreads();                             // B4
#pragma unroll
      for (int k = 0; k < 16; ++k){
        const float y2k  = z[k] * inv_a1 + y[k];
        const float clse = colbuf[j * 16 + k];
        const float lsn  = lmu_i + y2k - clse;
        z[k] += a1 * (expf(y[k]) - expf(lsn));
        ls[k] = lsn;
      }
    }
  }
}

extern "C" void kernel_launch(void* const* d_in, const int* in_sizes, int n_in,
                              void* d_out, int out_size, void* d_ws, size_t ws_size,
                              hipStream_t stream){
  const float* x    = (const float*)d_in[0];
  const int*   batch= (const int*)  d_in[1];
  const float* W1   = (const float*)d_in[2];
  const float* W2   = (const float*)d_in[3];
  const float* a1r  = (const float*)d_in[4];
  const float* a2r  = (const float*)d_in[5];
  const float* a3r  = (const float*)d_in[6];
  float* out = (float*)d_out;

  const int T  = in_sizes[1];        // rows of x
  const int Bn = out_size / 128;     // segments

  float* ws     = (float*)d_ws;
  float* scores = ws;                              // T floats
  float* w1t    = ws + ((T + 255) & ~255);         // 32768 floats

  k_transpose<<<128, 256, 0, stream>>>(W1, w1t);
  k_scores<<<1024, 256, 0, stream>>>(x, w1t, W2, scores, T);
  k_uot<<<Bn, 1024, 0, stream>>>(x, batch, scores, a1r, a2r, a3r, out, T);
}

// Round 2
// 503.298 us; speedup vs baseline: 1.0086x; 1.0086x over previous
//
#include <hip/hip_runtime.h>
#include <math.h>

#define NEGC -1000000000.0f

__device__ __forceinline__ float softplusf(float v){ return log1pf(expf(v)); }

// ---------------- Kernel 1: scores[t] = tanh(x[t]·W1[k,:]) · W2 ----------------
// 64 rows per block staged in LDS; thread (r=tid&63, q=tid>>6) computes the
// 64-k quarter [q*64, q*64+64) for row r. W1 accessed via wave-uniform address
// (readfirstlane) -> scalar s_load path; x via conflict-free ds_read_b128.
__global__ __launch_bounds__(256) void k_scores(const float* __restrict__ x,
                                                const float* __restrict__ W1,
                                                const float* __restrict__ W2,
                                                float* __restrict__ scores, int T){
  __shared__ float xs[64][132];     // pad 132: b128 reads land 8 words/bank (floor)
  __shared__ float scpart[4][64];
  const int tid  = threadIdx.x;
  const int r    = tid & 63;
  const int q    = tid >> 6;
  const int row0 = blockIdx.x * 64;

  // stage 64 rows x 128 floats, coalesced float4
#pragma unroll
  for (int i = 0; i < 8; ++i){
    int g  = tid + i * 256;          // float4 index in tile: 0..2047
    int rr = g >> 5;                 // row in tile (32 float4 per row)
    int cc = g & 31;
    int grow = row0 + rr; grow = (grow < T) ? grow : (T - 1);
    *(float4*)&xs[rr][cc * 4] = *(const float4*)(x + (size_t)grow * 128 + cc * 4);
  }
  __syncthreads();

  const int kbase = __builtin_amdgcn_readfirstlane(q * 64);
  float psum = 0.f;
  for (int kc = 0; kc < 8; ++kc){
    const float* wp = W1 + (size_t)(kbase + kc * 8) * 128;   // uniform -> s_load
    float acc[8];
#pragma unroll
    for (int kk = 0; kk < 8; ++kk) acc[kk] = 0.f;
#pragma unroll
    for (int d = 0; d < 128; d += 4){
      const float4 xv = *(const float4*)&xs[r][d];
#pragma unroll
      for (int kk = 0; kk < 8; ++kk){
        acc[kk] = fmaf(xv.x, wp[kk * 128 + d + 0], acc[kk]);
        acc[kk] = fmaf(xv.y, wp[kk * 128 + d + 1], acc[kk]);
        acc[kk] = fmaf(xv.z, wp[kk * 128 + d + 2], acc[kk]);
        acc[kk] = fmaf(xv.w, wp[kk * 128 + d + 3], acc[kk]);
      }
    }
#pragma unroll
    for (int kk = 0; kk < 8; ++kk)
      psum = fmaf(tanhf(acc[kk]), W2[kbase + kc * 8 + kk], psum);
  }
  scpart[q][r] = psum;
  __syncthreads();
  if (tid < 64){
    int row = row0 + tid;
    if (row < T)
      scores[row] = scpart[0][tid] + scpart[1][tid] + scpart[2][tid] + scpart[3][tid];
  }
}

// ---------------- Kernel 2: per-segment UOT-badmm + pooled output ----------------
// 1024 threads: thread (n = tid>>3, j = tid&7) owns row n, cols j*16..j*16+15.
__global__ __launch_bounds__(1024) void k_uot(const float* __restrict__ x,
                                              const int*   __restrict__ batch,
                                              const float* __restrict__ scores,
                                              const float* __restrict__ a1r,
                                              const float* __restrict__ a2r,
                                              const float* __restrict__ a3r,
                                              float* __restrict__ out, int T){
  __shared__ float wavebuf[16][128];
  __shared__ float colbuf[128];
  __shared__ float lq0s[128];
  __shared__ int   sseg[2];
  __shared__ float sred[2];

  const int b    = blockIdx.x;
  const int tid  = threadIdx.x;
  const int n    = tid >> 3;
  const int j    = tid & 7;
  const int wvi  = tid >> 6;
  const int lane = tid & 63;

  if (tid == 0){
    int lo = 0, hi = T;
    while (lo < hi){ int mid = (lo + hi) >> 1; if (batch[mid] <  b) lo = mid + 1; else hi = mid; }
    int s0 = lo;
    hi = T;
    while (lo < hi){ int mid = (lo + hi) >> 1; if (batch[mid] <= b) lo = mid + 1; else hi = mid; }
    sseg[0] = s0; sseg[1] = lo - s0;
  }
  __syncthreads();
  const int start = sseg[0];
  const int nb    = sseg[1];

  // ---- segment softmax over scores -> log q0 ----
  if (tid < 128) lq0s[tid] = (tid < nb) ? scores[start + tid] : NEGC;
  __syncthreads();
  if (wvi == 0){
    float v0 = lq0s[lane], v1 = lq0s[lane + 64];
    float m = fmaxf(v0, v1);
#pragma unroll
    for (int msk = 32; msk; msk >>= 1) m = fmaxf(m, __shfl_xor(m, msk, 64));
    float s = expf(v0 - m) + expf(v1 - m);   // masked lanes underflow to 0
#pragma unroll
    for (int msk = 32; msk; msk >>= 1) s += __shfl_xor(s, msk, 64);
    if (lane == 0){ sred[0] = m; sred[1] = s; }
  }
  __syncthreads();
  const float smax   = sred[0];
  const float sdenom = sred[1] + 1e-16f;
  if (tid < 128){
    float l = NEGC;
    if (tid < nb){
      float qv = expf(lq0s[tid] - smax) / sdenom;
      l = logf(qv + 1e-8f);
    }
    lq0s[tid] = l;
  }
  __syncthreads();

  const float a1 = softplusf(a1r[0]);
  const float a2 = softplusf(a2r[0]);
  const float a3 = softplusf(a3r[0]);
  const float inv_a1 = 1.f / a1;
  const float log_p0 = logf(1.0f / 128.0f + 1e-8f);

  // mu-recursion: data-independent scalars (logsumexp(log_s,axis=1) == log_mu_old)
  float lmu_use[3];
  lmu_use[0] = log_p0;
  {
    float z1 = 0.f, lp = log_p0;
#pragma unroll
    for (int i = 1; i < 3; ++i){
      float nm = (a1 * lp + a2 * log_p0 - z1) / (a1 + a2);
      z1 += a1 * (expf(nm) - expf(lp));
      lmu_use[i] = nm; lp = nm;
    }
  }
  // eta-recursion: per-row scalars (logsumexp(log_t,axis=2) == log_eta_old)
  const float lq0 = lq0s[n];
  float leta_use[4];
  leta_use[0] = lq0;
  {
    float z2 = 0.f, lp = lq0;
#pragma unroll
    for (int i = 1; i < 4; ++i){
      float nm = (a1 * lp + a3 * lq0 - z2) / (a1 + a3);
      z2 += a1 * (expf(nm) - expf(lp));
      leta_use[i] = nm; lp = nm;
    }
  }

  const bool valid = (n < nb);
  float xd[16], z[16], ls[16];
  {
    const float* xp = x + (size_t)(start + n) * 128 + j * 16;
#pragma unroll
    for (int k = 0; k < 16; k += 4){
      float4 v = valid ? *(const float4*)(xp + k) : make_float4(0.f, 0.f, 0.f, 0.f);
      xd[k] = v.x; xd[k+1] = v.y; xd[k+2] = v.z; xd[k+3] = v.w;
    }
    const float lsi = lq0 + log_p0;
#pragma unroll
    for (int k = 0; k < 16; ++k){ z[k] = 0.f; ls[k] = lsi; }
  }

#pragma unroll
  for (int it = 0; it < 4; ++it){
    const float leta_i = leta_use[it];
    float y[16];
    float rmax = -3.402823e38f;
#pragma unroll
    for (int k = 0; k < 16; ++k){
      y[k] = (xd[k] - z[k]) * inv_a1 + ls[k];
      rmax = fmaxf(rmax, y[k]);
    }
    rmax = fmaxf(rmax, __shfl_xor(rmax, 1, 64));
    rmax = fmaxf(rmax, __shfl_xor(rmax, 2, 64));
    rmax = fmaxf(rmax, __shfl_xor(rmax, 4, 64));
    float rsum = 0.f;
#pragma unroll
    for (int k = 0; k < 16; ++k) rsum += expf(y[k] - rmax);
    rsum += __shfl_xor(rsum, 1, 64);
    rsum += __shfl_xor(rsum, 2, 64);
    rsum += __shfl_xor(rsum, 4, 64);
    const float rlse = rmax + logf(rsum);
    const float lof  = leta_i - rlse;
#pragma unroll
    for (int k = 0; k < 16; ++k) y[k] += lof;     // y = log_t

    if (it == 3){
      // output: out[b,d] = 128 * sum_n xd * exp(log_t)
#pragma unroll
      for (int k = 0; k < 16; ++k){
        float v = xd[k] * expf(y[k]);
        v += __shfl_xor(v, 8, 64);
        v += __shfl_xor(v, 16, 64);
        v += __shfl_xor(v, 32, 64);
        if (lane < 8) wavebuf[wvi][lane * 16 + k] = v;
      }
      __syncthreads();
      if (tid < 128){
        float s = 0.f;
#pragma unroll
        for (int wq = 0; wq < 16; ++wq) s += wavebuf[wq][tid];
        out[(size_t)b * 128 + tid] = 128.f * s;
      }
    } else {
      const float lmu_i = lmu_use[it];
      // column max of y2 = z/a1 + log_t
#pragma unroll
      for (int k = 0; k < 16; ++k){
        float v = z[k] * inv_a1 + y[k];
        v = fmaxf(v, __shfl_xor(v, 8, 64));
        v = fmaxf(v, __shfl_xor(v, 16, 64));
        v = fmaxf(v, __shfl_xor(v, 32, 64));
        if (lane < 8) wavebuf[wvi][lane * 16 + k] = v;
      }
      __syncthreads();                             // B1
      if (tid < 128){
        float m = -3.402823e38f;
#pragma unroll
        for (int wq = 0; wq < 16; ++wq) m = fmaxf(m, wavebuf[wq][tid]);
        colbuf[tid] = m;
      }
      __syncthreads();                             // B2
      // column sum of exp(y2 - cmax)
#pragma unroll
      for (int k = 0; k < 16; ++k){
        const float y2k = z[k] * inv_a1 + y[k];
        float v = expf(y2k - colbuf[j * 16 + k]);
        v += __shfl_xor(v, 8, 64);
        v += __shfl_xor(v, 16, 64);
        v += __shfl_xor(v, 32, 64);
        if (lane < 8) wavebuf[wvi][lane * 16 + k] = v;
      }
      __syncthreads();                             // B3
      if (tid < 128){
        float s = 0.f;
#pragma unroll
        for (int wq = 0; wq < 16; ++wq) s += wavebuf[wq][tid];
        colbuf[tid] = colbuf[tid] + logf(s);       // clse = cmax + log(csum)
      }
      __syncthreads();                             // B4
#pragma unroll
      for (int k = 0; k < 16; ++k){
        const float y2k  = z[k] * inv_a1 + y[k];
        const float clse = colbuf[j * 16 + k];
        const float lsn  = lmu_i + y2k - clse;
        z[k] += a1 * (expf(y[k]) - expf(lsn));
        ls[k] = lsn;
      }
    }
  }
}

extern "C" void kernel_launch(void* const* d_in, const int* in_sizes, int n_in,
                              void* d_out, int out_size, void* d_ws, size_t ws_size,
                              hipStream_t stream){
  const float* x    = (const float*)d_in[0];
  const int*   batch= (const int*)  d_in[1];
  const float* W1   = (const float*)d_in[2];
  const float* W2   = (const float*)d_in[3];
  const float* a1r  = (const float*)d_in[4];
  const float* a2r  = (const float*)d_in[5];
  const float* a3r  = (const float*)d_in[6];
  float* out = (float*)d_out;

  const int T  = in_sizes[1];        // rows of x
  const int Bn = out_size / 128;     // segments

  float* scores = (float*)d_ws;      // T floats

  const int tiles = (T + 63) / 64;
  k_scores<<<tiles, 256, 0, stream>>>(x, W1, W2, scores, T);
  k_uot<<<Bn, 1024, 0, stream>>>(x, batch, scores, a1r, a2r, a3r, out, T);
}

// Round 3
// 330.909 us; speedup vs baseline: 1.5340x; 1.5210x over previous
//
#include <hip/hip_runtime.h>
#include <math.h>

#define NEGC -1000000000.0f

__device__ __forceinline__ float softplusf(float v){ return log1pf(expf(v)); }

// ---------------- Kernel A: W1 (256x128) -> w1t (128x256) ----------------
__global__ __launch_bounds__(256) void k_transpose(const float* __restrict__ W1,
                                                   float* __restrict__ w1t){
  int i = blockIdx.x * 256 + threadIdx.x;   // 0..32767
  if (i < 256 * 128){
    int k = i >> 7, d = i & 127;
    w1t[d * 256 + k] = W1[i];
  }
}

// ---------------- Kernel B: segment starts via parallel binary search ----------------
__global__ __launch_bounds__(256) void k_seg(const int* __restrict__ batch,
                                             int* __restrict__ starts, int T, int Bn){
  int t = blockIdx.x * 256 + threadIdx.x;
  if (t > Bn) return;
  if (t == Bn){ starts[Bn] = T; return; }
  int lo = 0, hi = T;
  while (lo < hi){ int mid = (lo + hi) >> 1; if (batch[mid] < t) lo = mid + 1; else hi = mid; }
  starts[t] = lo;
}

// ---------------- Kernel C: scores[t] = tanh(x[t]·W1[k,:]) · W2 ----------------
// 256 threads = 16 ty x 16 tx. Thread: 4 rows (ty*4..+3) x 16 k (tx*16..+15).
// x tile transposed in LDS (xs_t[d][row], pad 65); W read from w1t[d][k] (L2).
__global__ __launch_bounds__(256) void k_scores(const float* __restrict__ x,
                                                const float* __restrict__ w1t,
                                                const float* __restrict__ W2,
                                                float* __restrict__ scores, int T){
  __shared__ float xs_t[128][65];
  const int tid  = threadIdx.x;
  const int ty   = tid >> 4;
  const int tx   = tid & 15;
  const int row0 = blockIdx.x * 64;

  // stage 64 rows x 128 d, transposed: xs_t[d][row] = x[row0+row][d]
#pragma unroll
  for (int i = 0; i < 8; ++i){
    int g   = tid + i * 256;            // float4 index 0..2047
    int rr  = g >> 5;                   // row in tile
    int c4  = g & 31;                   // float4 col
    int grow = row0 + rr; grow = (grow < T) ? grow : (T - 1);
    const float4 v = *(const float4*)(x + (size_t)grow * 128 + c4 * 4);
    xs_t[c4 * 4 + 0][rr] = v.x;
    xs_t[c4 * 4 + 1][rr] = v.y;
    xs_t[c4 * 4 + 2][rr] = v.z;
    xs_t[c4 * 4 + 3][rr] = v.w;
  }
  __syncthreads();

  float acc[4][16];
#pragma unroll
  for (int i = 0; i < 4; ++i)
#pragma unroll
    for (int kk = 0; kk < 16; ++kk) acc[i][kk] = 0.f;

  const float* wbase = w1t + tx * 16;
#pragma unroll 2
  for (int d = 0; d < 128; ++d){
    const float4 xv = *(const float4*)&xs_t[d][ty * 4];   // 4 rows, one b128
    float4 wv0 = *(const float4*)(wbase + (size_t)d * 256 + 0);
    float4 wv1 = *(const float4*)(wbase + (size_t)d * 256 + 4);
    float4 wv2 = *(const float4*)(wbase + (size_t)d * 256 + 8);
    float4 wv3 = *(const float4*)(wbase + (size_t)d * 256 + 12);
    const float w[16] = {wv0.x,wv0.y,wv0.z,wv0.w, wv1.x,wv1.y,wv1.z,wv1.w,
                         wv2.x,wv2.y,wv2.z,wv2.w, wv3.x,wv3.y,wv3.z,wv3.w};
    const float xr[4] = {xv.x, xv.y, xv.z, xv.w};
#pragma unroll
    for (int i = 0; i < 4; ++i)
#pragma unroll
      for (int kk = 0; kk < 16; ++kk)
        acc[i][kk] = fmaf(xr[i], w[kk], acc[i][kk]);
  }

  // tanh + W2 dot (fast tanh via exp2-based __expf; clamp for inf safety)
  float psum[4] = {0.f, 0.f, 0.f, 0.f};
  const float4 w2a = *(const float4*)(W2 + tx * 16 + 0);
  const float4 w2b = *(const float4*)(W2 + tx * 16 + 4);
  const float4 w2c = *(const float4*)(W2 + tx * 16 + 8);
  const float4 w2d = *(const float4*)(W2 + tx * 16 + 12);
  const float w2[16] = {w2a.x,w2a.y,w2a.z,w2a.w, w2b.x,w2b.y,w2b.z,w2b.w,
                        w2c.x,w2c.y,w2c.z,w2c.w, w2d.x,w2d.y,w2d.z,w2d.w};
#pragma unroll
  for (int kk = 0; kk < 16; ++kk)
#pragma unroll
    for (int i = 0; i < 4; ++i){
      float a = fminf(fmaxf(acc[i][kk], -15.f), 15.f);
      float e = __expf(2.f * a);
      psum[i] = fmaf((e - 1.f) / (e + 1.f), w2[kk], psum[i]);
    }

  // reduce across tx (lane bits 0..3)
#pragma unroll
  for (int i = 0; i < 4; ++i){
    psum[i] += __shfl_xor(psum[i], 1, 64);
    psum[i] += __shfl_xor(psum[i], 2, 64);
    psum[i] += __shfl_xor(psum[i], 4, 64);
    psum[i] += __shfl_xor(psum[i], 8, 64);
  }
  if (tx == 0){
#pragma unroll
    for (int i = 0; i < 4; ++i){
      int row = row0 + ty * 4 + i;
      if (row < T) scores[row] = psum[i];
    }
  }
}

// ---------------- Kernel D: per-segment UOT-badmm + pooled output ----------------
// thread (n = tid>>3, j = tid&7) owns row n, cols j*16..j*16+15.
// Waves beyond ceil(max(nb*8,128)/64) exit early (s_barrier accounts for them).
__global__ __launch_bounds__(1024) void k_uot(const float* __restrict__ x,
                                              const int*   __restrict__ starts,
                                              const float* __restrict__ scores,
                                              const float* __restrict__ a1r,
                                              const float* __restrict__ a2r,
                                              const float* __restrict__ a3r,
                                              float* __restrict__ out){
  __shared__ float mbuf[16][128];
  __shared__ float sbuf[16][128];
  __shared__ float colbuf[128];
  __shared__ float lq0s[128];
  __shared__ float sred[2];

  const int b     = blockIdx.x;
  const int tid   = threadIdx.x;
  const int start = starts[b];
  const int nb    = starts[b + 1] - start;

  if (nb <= 0){
    if (tid < 128) out[(size_t)b * 128 + tid] = 0.f;
    return;
  }
  int amax = nb * 8; if (amax < 128) amax = 128;
  amax = (amax + 63) & ~63;
  if (tid >= amax) return;                 // exited waves; barrier releases on them
  const int NW = amax >> 6;                // live waves

  const int n    = tid >> 3;
  const int j    = tid & 7;
  const int wvi  = tid >> 6;
  const int lane = tid & 63;

  // ---- segment softmax over scores -> log q0 ----
  if (tid < 128) lq0s[tid] = (tid < nb) ? scores[start + tid] : NEGC;
  __syncthreads();
  if (wvi == 0){
    float v0 = lq0s[lane], v1 = lq0s[lane + 64];
    float m = fmaxf(v0, v1);
#pragma unroll
    for (int msk = 32; msk; msk >>= 1) m = fmaxf(m, __shfl_xor(m, msk, 64));
    float s = __expf(v0 - m) + __expf(v1 - m);
#pragma unroll
    for (int msk = 32; msk; msk >>= 1) s += __shfl_xor(s, msk, 64);
    if (lane == 0){ sred[0] = m; sred[1] = s; }
  }
  __syncthreads();
  const float smax   = sred[0];
  const float sdenom = sred[1] + 1e-16f;
  if (tid < 128){
    float l = NEGC;
    if (tid < nb){
      float qv = __expf(lq0s[tid] - smax) / sdenom;
      l = __logf(qv + 1e-8f);
    }
    lq0s[tid] = l;
  }
  __syncthreads();

  const float a1 = softplusf(a1r[0]);
  const float a2 = softplusf(a2r[0]);
  const float a3 = softplusf(a3r[0]);
  const float inv_a1 = 1.f / a1;
  const float log_p0 = logf(1.0f / 128.0f + 1e-8f);

  // mu-recursion (data-independent scalars)
  float lmu_use[3];
  lmu_use[0] = log_p0;
  {
    float z1 = 0.f, lp = log_p0;
#pragma unroll
    for (int i = 1; i < 3; ++i){
      float nm = (a1 * lp + a2 * log_p0 - z1) / (a1 + a2);
      z1 += a1 * (__expf(nm) - __expf(lp));
      lmu_use[i] = nm; lp = nm;
    }
  }
  // eta-recursion (per-row scalars)
  const float lq0 = lq0s[n];
  float leta_use[4];
  leta_use[0] = lq0;
  {
    float z2 = 0.f, lp = lq0;
#pragma unroll
    for (int i = 1; i < 4; ++i){
      float nm = (a1 * lp + a3 * lq0 - z2) / (a1 + a3);
      z2 += a1 * (__expf(nm) - __expf(lp));
      leta_use[i] = nm; lp = nm;
    }
  }

  const bool valid = (n < nb);
  float xd[16], z[16], ls[16];
  {
    const float* xp = x + (size_t)(start + n) * 128 + j * 16;
#pragma unroll
    for (int k = 0; k < 16; k += 4){
      float4 v = valid ? *(const float4*)(xp + k) : make_float4(0.f, 0.f, 0.f, 0.f);
      xd[k] = v.x; xd[k+1] = v.y; xd[k+2] = v.z; xd[k+3] = v.w;
    }
    const float lsi = lq0 + log_p0;
#pragma unroll
    for (int k = 0; k < 16; ++k){ z[k] = 0.f; ls[k] = lsi; }
  }

#pragma unroll
  for (int it = 0; it < 4; ++it){
    const float leta_i = leta_use[it];
    float y[16];
    float rmax = -3.402823e38f;
#pragma unroll
    for (int k = 0; k < 16; ++k){
      y[k] = (xd[k] - z[k]) * inv_a1 + ls[k];
      rmax = fmaxf(rmax, y[k]);
    }
    rmax = fmaxf(rmax, __shfl_xor(rmax, 1, 64));
    rmax = fmaxf(rmax, __shfl_xor(rmax, 2, 64));
    rmax = fmaxf(rmax, __shfl_xor(rmax, 4, 64));
    float rsum = 0.f;
#pragma unroll
    for (int k = 0; k < 16; ++k) rsum += __expf(y[k] - rmax);
    rsum += __shfl_xor(rsum, 1, 64);
    rsum += __shfl_xor(rsum, 2, 64);
    rsum += __shfl_xor(rsum, 4, 64);
    const float rlse = rmax + __logf(rsum);
    const float lof  = leta_i - rlse;
#pragma unroll
    for (int k = 0; k < 16; ++k) y[k] += lof;     // y = log_t

    if (it == 3){
      // out[b,d] = 128 * sum_n xd * exp(log_t)
#pragma unroll
      for (int k = 0; k < 16; ++k){
        float v = xd[k] * __expf(y[k]);
        v += __shfl_xor(v, 8, 64);
        v += __shfl_xor(v, 16, 64);
        v += __shfl_xor(v, 32, 64);
        if (lane < 8) mbuf[wvi][lane * 16 + k] = v;
      }
      __syncthreads();
      if (tid < 128){
        float s = 0.f;
        for (int wq = 0; wq < NW; ++wq) s += mbuf[wq][tid];
        out[(size_t)b * 128 + tid] = 128.f * s;
      }
    } else {
      const float lmu_i = lmu_use[it];
      // fused column (max, sum) pass: y2 = z/a1 + log_t
      float y2[16];
#pragma unroll
      for (int k = 0; k < 16; ++k){
        y2[k] = z[k] * inv_a1 + y[k];
        float m = y2[k];
        m = fmaxf(m, __shfl_xor(m, 8, 64));
        m = fmaxf(m, __shfl_xor(m, 16, 64));
        m = fmaxf(m, __shfl_xor(m, 32, 64));
        float e = __expf(y2[k] - m);
        e += __shfl_xor(e, 8, 64);
        e += __shfl_xor(e, 16, 64);
        e += __shfl_xor(e, 32, 64);
        if (lane < 8){
          mbuf[wvi][lane * 16 + k] = m;
          sbuf[wvi][lane * 16 + k] = e;
        }
      }
      __syncthreads();                             // B1
      if (tid < 128){
        float m = -3.402823e38f;
        for (int wq = 0; wq < NW; ++wq) m = fmaxf(m, mbuf[wq][tid]);
        float s = 0.f;
        for (int wq = 0; wq < NW; ++wq) s += sbuf[wq][tid] * __expf(mbuf[wq][tid] - m);
        colbuf[tid] = m + __logf(s);               // column LSE
      }
      __syncthreads();                             // B2
#pragma unroll
      for (int k = 0; k < 16; ++k){
        const float clse = colbuf[j * 16 + k];
        const float lsn  = lmu_i + y2[k] - clse;
        z[k] += a1 * (__expf(y[k]) - __expf(lsn));
        ls[k] = lsn;
      }
    }
  }
}

extern "C" void kernel_launch(void* const* d_in, const int* in_sizes, int n_in,
                              void* d_out, int out_size, void* d_ws, size_t ws_size,
                              hipStream_t stream){
  const float* x    = (const float*)d_in[0];
  const int*   batch= (const int*)  d_in[1];
  const float* W1   = (const float*)d_in[2];
  const float* W2   = (const float*)d_in[3];
  const float* a1r  = (const float*)d_in[4];
  const float* a2r  = (const float*)d_in[5];
  const float* a3r  = (const float*)d_in[6];
  float* out = (float*)d_out;

  const int T  = in_sizes[1];        // rows of x
  const int Bn = out_size / 128;     // segments

  float* ws     = (float*)d_ws;
  float* scores = ws;                              // T floats
  float* w1t    = ws + ((T + 255) & ~255);         // 32768 floats
  int*   starts = (int*)(w1t + 32768);             // Bn+1 ints

  k_transpose<<<128, 256, 0, stream>>>(W1, w1t);
  k_seg<<<(Bn + 256) / 256, 256, 0, stream>>>(batch, starts, T, Bn);
  const int tiles = (T + 63) / 64;
  k_scores<<<tiles, 256, 0, stream>>>(x, w1t, W2, scores, T);
  k_uot<<<Bn, 1024, 0, stream>>>(x, starts, scores, a1r, a2r, a3r, out);
}

// Round 4
// 172.238 us; speedup vs baseline: 2.9471x; 1.9212x over previous
//
#include <hip/hip_runtime.h>
#include <math.h>

#define NEGC -1000000000.0f

using f32x4 = __attribute__((ext_vector_type(4))) float;
using s16x8 = __attribute__((ext_vector_type(8))) short;

__device__ __forceinline__ float softplusf(float v){ return log1pf(expf(v)); }
__device__ __forceinline__ short f2bf(float f){   // RNE f32->bf16
  unsigned u = __float_as_uint(f);
  unsigned r = (u + 0x7fffu + ((u >> 16) & 1u)) >> 16;
  return (short)r;
}

// ---------------- Kernel A: pack W1 (256x128 f32) into bf16 B-fragments ----------------
// wpack[((kt*4+dt)*64 + lane)*8 + e] = bf16( W1[kt*16 + lane%16][dt*32 + (lane/16)*8 + e] )
__global__ __launch_bounds__(256) void k_pack(const float* __restrict__ W1,
                                              short* __restrict__ wpack){
  int gid  = blockIdx.x * 256 + threadIdx.x;   // 0..4095
  int lane = gid & 63;
  int ft   = gid >> 6;                         // 0..63
  int kt   = ft >> 2;
  int dt   = ft & 3;
  const float* src = W1 + (size_t)(kt * 16 + (lane & 15)) * 128 + dt * 32 + (lane >> 4) * 8;
  short o[8];
#pragma unroll
  for (int e = 0; e < 8; ++e) o[e] = f2bf(src[e]);
  *(s16x8*)(wpack + (size_t)gid * 8) = *(const s16x8*)o;
}

// ---------------- Kernel B: segment starts via parallel binary search ----------------
__global__ __launch_bounds__(256) void k_seg(const int* __restrict__ batch,
                                             int* __restrict__ starts, int T, int Bn){
  int t = blockIdx.x * 256 + threadIdx.x;
  if (t > Bn) return;
  if (t == Bn){ starts[Bn] = T; return; }
  int lo = 0, hi = T;
  while (lo < hi){ int mid = (lo + hi) >> 1; if (batch[mid] < t) lo = mid + 1; else hi = mid; }
  starts[t] = lo;
}

// ---------------- Kernel C: scores via bf16 MFMA ----------------
// 64 rows/block, 4 waves: wave (wm=w&1, wn=w>>1) -> rows wm*32..+31, k-cols wn*128..+127.
// x tile staged bf16 in LDS with XOR swizzle (byte ^= (row&7)<<4).
__global__ __launch_bounds__(256) void k_scores(const float* __restrict__ x,
                                                const short* __restrict__ wpack,
                                                const float* __restrict__ W2,
                                                float* __restrict__ scores, int T){
  __shared__ __align__(16) short xs[64 * 128];
  __shared__ float scpart[2][64];
  const int tid  = threadIdx.x;
  const int lane = tid & 63;
  const int w    = tid >> 6;
  const int wm   = w & 1;
  const int wn   = w >> 1;
  const int row0 = blockIdx.x * 64;

  // stage + convert 64x128 f32 -> bf16, swizzled
#pragma unroll
  for (int it = 0; it < 4; ++it){
    int L  = (it * 256 + tid) * 8;       // linear element idx
    int rr = L >> 7;
    int dc = L & 127;
    int grow = row0 + rr; grow = (grow < T) ? grow : (T - 1);
    const float4 v0 = *(const float4*)(x + (size_t)grow * 128 + dc);
    const float4 v1 = *(const float4*)(x + (size_t)grow * 128 + dc + 4);
    short o[8] = {f2bf(v0.x), f2bf(v0.y), f2bf(v0.z), f2bf(v0.w),
                  f2bf(v1.x), f2bf(v1.y), f2bf(v1.z), f2bf(v1.w)};
    int byte = rr * 256 + ((dc * 2) ^ ((rr & 7) << 4));
    *(s16x8*)((char*)xs + byte) = *(const s16x8*)o;
  }
  __syncthreads();

  f32x4 acc[2][8];
#pragma unroll
  for (int mt = 0; mt < 2; ++mt)
#pragma unroll
    for (int kt = 0; kt < 8; ++kt) acc[mt][kt] = (f32x4){0.f, 0.f, 0.f, 0.f};

  const s16x8* wp = (const s16x8*)wpack;
#pragma unroll
  for (int dt = 0; dt < 4; ++dt){
    s16x8 av[2];
#pragma unroll
    for (int mt = 0; mt < 2; ++mt){
      int arow = wm * 32 + mt * 16 + (lane & 15);
      int byte = arow * 256 + ((dt * 64 + (lane >> 4) * 16) ^ ((arow & 7) << 4));
      av[mt] = *(const s16x8*)((const char*)xs + byte);
    }
#pragma unroll
    for (int kt = 0; kt < 8; ++kt){
      s16x8 wv = wp[(size_t)(((wn * 8 + kt) * 4 + dt) << 6) + lane];
#pragma unroll
      for (int mt = 0; mt < 2; ++mt)
        acc[mt][kt] = __builtin_amdgcn_mfma_f32_16x16x32_bf16(av[mt], wv, acc[mt][kt], 0, 0, 0);
    }
  }

  // epilogue: psum = sum_k tanh(acc) * W2[k]
  float psum[2][4] = {{0.f,0.f,0.f,0.f},{0.f,0.f,0.f,0.f}};
#pragma unroll
  for (int kt = 0; kt < 8; ++kt){
    const float w2v = W2[(wn * 8 + kt) * 16 + (lane & 15)];
#pragma unroll
    for (int mt = 0; mt < 2; ++mt)
#pragma unroll
      for (int r = 0; r < 4; ++r){
        float a = fminf(fmaxf(acc[mt][kt][r], -15.f), 15.f);
        float e = __expf(2.f * a);
        psum[mt][r] = fmaf((e - 1.f) / (e + 1.f), w2v, psum[mt][r]);
      }
  }
#pragma unroll
  for (int mt = 0; mt < 2; ++mt)
#pragma unroll
    for (int r = 0; r < 4; ++r){
      float v = psum[mt][r];
      v += __shfl_xor(v, 1, 64); v += __shfl_xor(v, 2, 64);
      v += __shfl_xor(v, 4, 64); v += __shfl_xor(v, 8, 64);
      if ((lane & 15) == 0)
        scpart[wn][wm * 32 + mt * 16 + (lane >> 4) * 4 + r] = v;
    }
  __syncthreads();
  if (tid < 64){
    int row = row0 + tid;
    if (row < T) scores[row] = scpart[0][tid] + scpart[1][tid];
  }
}

// ---------------- Kernel D: per-segment UOT-badmm + pooled output ----------------
// (unchanged from round 3)
__global__ __launch_bounds__(1024) void k_uot(const float* __restrict__ x,
                                              const int*   __restrict__ starts,
                                              const float* __restrict__ scores,
                                              const float* __restrict__ a1r,
                                              const float* __restrict__ a2r,
                                              const float* __restrict__ a3r,
                                              float* __restrict__ out){
  __shared__ float mbuf[16][128];
  __shared__ float sbuf[16][128];
  __shared__ float colbuf[128];
  __shared__ float lq0s[128];
  __shared__ float sred[2];

  const int b     = blockIdx.x;
  const int tid   = threadIdx.x;
  const int start = starts[b];
  const int nb    = starts[b + 1] - start;

  if (nb <= 0){
    if (tid < 128) out[(size_t)b * 128 + tid] = 0.f;
    return;
  }
  int amax = nb * 8; if (amax < 128) amax = 128;
  amax = (amax + 63) & ~63;
  if (tid >= amax) return;
  const int NW = amax >> 6;

  const int n    = tid >> 3;
  const int j    = tid & 7;
  const int wvi  = tid >> 6;
  const int lane = tid & 63;

  if (tid < 128) lq0s[tid] = (tid < nb) ? scores[start + tid] : NEGC;
  __syncthreads();
  if (wvi == 0){
    float v0 = lq0s[lane], v1 = lq0s[lane + 64];
    float m = fmaxf(v0, v1);
#pragma unroll
    for (int msk = 32; msk; msk >>= 1) m = fmaxf(m, __shfl_xor(m, msk, 64));
    float s = __expf(v0 - m) + __expf(v1 - m);
#pragma unroll
    for (int msk = 32; msk; msk >>= 1) s += __shfl_xor(s, msk, 64);
    if (lane == 0){ sred[0] = m; sred[1] = s; }
  }
  __syncthreads();
  const float smax   = sred[0];
  const float sdenom = sred[1] + 1e-16f;
  if (tid < 128){
    float l = NEGC;
    if (tid < nb){
      float qv = __expf(lq0s[tid] - smax) / sdenom;
      l = __logf(qv + 1e-8f);
    }
    lq0s[tid] = l;
  }
  __syncthreads();

  const float a1 = softplusf(a1r[0]);
  const float a2 = softplusf(a2r[0]);
  const float a3 = softplusf(a3r[0]);
  const float inv_a1 = 1.f / a1;
  const float log_p0 = logf(1.0f / 128.0f + 1e-8f);

  float lmu_use[3];
  lmu_use[0] = log_p0;
  {
    float z1 = 0.f, lp = log_p0;
#pragma unroll
    for (int i = 1; i < 3; ++i){
      float nm = (a1 * lp + a2 * log_p0 - z1) / (a1 + a2);
      z1 += a1 * (__expf(nm) - __expf(lp));
      lmu_use[i] = nm; lp = nm;
    }
  }
  const float lq0 = lq0s[n];
  float leta_use[4];
  leta_use[0] = lq0;
  {
    float z2 = 0.f, lp = lq0;
#pragma unroll
    for (int i = 1; i < 4; ++i){
      float nm = (a1 * lp + a3 * lq0 - z2) / (a1 + a3);
      z2 += a1 * (__expf(nm) - __expf(lp));
      leta_use[i] = nm; lp = nm;
    }
  }

  const bool valid = (n < nb);
  float xd[16], z[16], ls[16];
  {
    const float* xp = x + (size_t)(start + n) * 128 + j * 16;
#pragma unroll
    for (int k = 0; k < 16; k += 4){
      float4 v = valid ? *(const float4*)(xp + k) : make_float4(0.f, 0.f, 0.f, 0.f);
      xd[k] = v.x; xd[k+1] = v.y; xd[k+2] = v.z; xd[k+3] = v.w;
    }
    const float lsi = lq0 + log_p0;
#pragma unroll
    for (int k = 0; k < 16; ++k){ z[k] = 0.f; ls[k] = lsi; }
  }

#pragma unroll
  for (int it = 0; it < 4; ++it){
    const float leta_i = leta_use[it];
    float y[16];
    float rmax = -3.402823e38f;
#pragma unroll
    for (int k = 0; k < 16; ++k){
      y[k] = (xd[k] - z[k]) * inv_a1 + ls[k];
      rmax = fmaxf(rmax, y[k]);
    }
    rmax = fmaxf(rmax, __shfl_xor(rmax, 1, 64));
    rmax = fmaxf(rmax, __shfl_xor(rmax, 2, 64));
    rmax = fmaxf(rmax, __shfl_xor(rmax, 4, 64));
    float rsum = 0.f;
#pragma unroll
    for (int k = 0; k < 16; ++k) rsum += __expf(y[k] - rmax);
    rsum += __shfl_xor(rsum, 1, 64);
    rsum += __shfl_xor(rsum, 2, 64);
    rsum += __shfl_xor(rsum, 4, 64);
    const float rlse = rmax + __logf(rsum);
    const float lof  = leta_i - rlse;
#pragma unroll
    for (int k = 0; k < 16; ++k) y[k] += lof;

    if (it == 3){
#pragma unroll
      for (int k = 0; k < 16; ++k){
        float v = xd[k] * __expf(y[k]);
        v += __shfl_xor(v, 8, 64);
        v += __shfl_xor(v, 16, 64);
        v += __shfl_xor(v, 32, 64);
        if (lane < 8) mbuf[wvi][lane * 16 + k] = v;
      }
      __syncthreads();
      if (tid < 128){
        float s = 0.f;
        for (int wq = 0; wq < NW; ++wq) s += mbuf[wq][tid];
        out[(size_t)b * 128 + tid] = 128.f * s;
      }
    } else {
      const float lmu_i = lmu_use[it];
      float y2[16];
#pragma unroll
      for (int k = 0; k < 16; ++k){
        y2[k] = z[k] * inv_a1 + y[k];
        float m = y2[k];
        m = fmaxf(m, __shfl_xor(m, 8, 64));
        m = fmaxf(m, __shfl_xor(m, 16, 64));
        m = fmaxf(m, __shfl_xor(m, 32, 64));
        float e = __expf(y2[k] - m);
        e += __shfl_xor(e, 8, 64);
        e += __shfl_xor(e, 16, 64);
        e += __shfl_xor(e, 32, 64);
        if (lane < 8){
          mbuf[wvi][lane * 16 + k] = m;
          sbuf[wvi][lane * 16 + k] = e;
        }
      }
      __syncthreads();
      if (tid < 128){
        float m = -3.402823e38f;
        for (int wq = 0; wq < NW; ++wq) m = fmaxf(m, mbuf[wq][tid]);
        float s = 0.f;
        for (int wq = 0; wq < NW; ++wq) s += sbuf[wq][tid] * __expf(mbuf[wq][tid] - m);
        colbuf[tid] = m + __logf(s);
      }
      __syncthreads();
#pragma unroll
      for (int k = 0; k < 16; ++k){
        const float clse = colbuf[j * 16 + k];
        const float lsn  = lmu_i + y2[k] - clse;
        z[k] += a1 * (__expf(y[k]) - __expf(lsn));
        ls[k] = lsn;
      }
    }
  }
}

extern "C" void kernel_launch(void* const* d_in, const int* in_sizes, int n_in,
                              void* d_out, int out_size, void* d_ws, size_t ws_size,
                              hipStream_t stream){
  const float* x    = (const float*)d_in[0];
  const int*   batch= (const int*)  d_in[1];
  const float* W1   = (const float*)d_in[2];
  const float* W2   = (const float*)d_in[3];
  const float* a1r  = (const float*)d_in[4];
  const float* a2r  = (const float*)d_in[5];
  const float* a3r  = (const float*)d_in[6];
  float* out = (float*)d_out;

  const int T  = in_sizes[1];        // rows of x
  const int Bn = out_size / 128;     // segments

  float* ws     = (float*)d_ws;
  float* scores = ws;                              // T floats
  short* wpack  = (short*)(ws + ((T + 255) & ~255));  // 32768 bf16
  int*   starts = (int*)(wpack + 32768);           // Bn+1 ints

  k_pack<<<16, 256, 0, stream>>>(W1, wpack);
  k_seg<<<(Bn + 256) / 256, 256, 0, stream>>>(batch, starts, T, Bn);
  const int tiles = (T + 63) / 64;
  k_scores<<<tiles, 256, 0, stream>>>(x, wpack, W2, scores, T);
  k_uot<<<Bn, 1024, 0, stream>>>(x, starts, scores, a1r, a2r, a3r, out);
}